// Round 9
// baseline (237.330 us; speedup 1.0000x reference)
//
#include <hip/hip_runtime.h>
#include <hip/hip_bf16.h>
#include <stdint.h>

// Shapes
#define DIM      1024
#define D_STATE  16
#define D_CONV   4
#define D_INNER  2048
#define DT_RANK  64
#define BATCH    2
#define SEQ      1024
#define MROWS    (BATCH * SEQ)            // 2048
#define NPROJ    (2 * D_INNER)            // 4096
#define XDBL_K   (DT_RANK + 2 * D_STATE)  // 96

// chunked scan
#define LC       32
#define NC       (SEQ / LC)               // 32
#define SLANES   (BATCH * D_INNER * D_STATE) // 65536

typedef __attribute__((ext_vector_type(8))) short short8;
typedef __attribute__((ext_vector_type(4))) float f32x4;
typedef unsigned short ushort_t;

__device__ __forceinline__ unsigned short f2bf(float f) {
    __hip_bfloat16 b = __float2bfloat16(f);
    return *reinterpret_cast<unsigned short*>(&b);
}
__device__ __forceinline__ float bf2f(unsigned short u) {
    __hip_bfloat16 b;
    *reinterpret_cast<unsigned short*>(&b) = u;
    return __bfloat162float(b);
}

__device__ __forceinline__ void gload_lds16(const unsigned short* g, unsigned short* l) {
    __builtin_amdgcn_global_load_lds(
        (const __attribute__((address_space(1))) void*)g,
        (__attribute__((address_space(3))) void*)l,
        16, 0, 0);
}

// ---------------------------------------------------------------------------
// Preamble: split all fp32 GEMM operand tensors into planar bf16 hi/lo.
// ---------------------------------------------------------------------------
#define SG0 524288    // x        granules (K/4 per row)
#define SG1 1048576   // in_w
#define SG2 65536     // xproj (128 rows pad)
#define SG3 32768     // dt_w
#define SG4 524288    // out_w
#define SPLIT_GRANULES (SG0 + SG1 + SG2 + SG3 + SG4)   // 2195456

__global__ __launch_bounds__(256) void split_all(
    const float* __restrict__ x,   const float* __restrict__ in_w,
    const float* __restrict__ xpw, const float* __restrict__ dtw,
    const float* __restrict__ ow,
    ushort_t* __restrict__ xh,   ushort_t* __restrict__ xl,
    ushort_t* __restrict__ iwh,  ushort_t* __restrict__ iwl,
    ushort_t* __restrict__ xph,  ushort_t* __restrict__ xpl,
    ushort_t* __restrict__ dth,  ushort_t* __restrict__ dtl,
    ushort_t* __restrict__ owh,  ushort_t* __restrict__ owl)
{
    int g = blockIdx.x * 256 + threadIdx.x;
    const float* src; int K, rows_src; ushort_t *dh, *dl;
    if (g < SG0)                      { src = x;    K = 1024; rows_src = 2048; dh = xh;  dl = xl; }
    else if ((g -= SG0) < SG1)        { src = in_w; K = 1024; rows_src = 4096; dh = iwh; dl = iwl; }
    else if ((g -= SG1) < SG2)        { src = xpw;  K = 2048; rows_src = 96;   dh = xph; dl = xpl; }
    else if ((g -= SG2) < SG3)        { src = dtw;  K = 64;   rows_src = 2048; dh = dth; dl = dtl; }
    else                              { g -= SG3;   src = ow; K = 2048; rows_src = 1024; dh = owh; dl = owl; }

    const int kq = K >> 2;
    const int r = g / kq;
    const int k4 = (g - r * kq) << 2;
    float4 v = make_float4(0.f, 0.f, 0.f, 0.f);
    if (r < rows_src)
        v = *reinterpret_cast<const float4*>(src + (size_t)r * K + k4);
    const unsigned short h0 = f2bf(v.x), h1 = f2bf(v.y), h2 = f2bf(v.z), h3 = f2bf(v.w);
    const unsigned short l0 = f2bf(v.x - bf2f(h0)), l1 = f2bf(v.y - bf2f(h1));
    const unsigned short l2 = f2bf(v.z - bf2f(h2)), l3 = f2bf(v.w - bf2f(h3));
    *reinterpret_cast<ushort4*>(dh + (size_t)r * K + k4) = make_ushort4(h0, h1, h2, h3);
    *reinterpret_cast<ushort4*>(dl + (size_t)r * K + k4) = make_ushort4(l0, l1, l2, l3);
}

// ---------------------------------------------------------------------------
// Planar 3-pass bf16 MFMA GEMM (NT), BK=32 double-buffer with COUNTED vmcnt:
// per tile: STAGE(next) -> s_waitcnt vmcnt(8) (current tile's loads, issued
// one compute-phase ago -> already done) -> raw s_barrier -> 48 MFMA ->
// raw s_barrier. Next tile's 8 loads stay in flight across the whole compute.
// No vmcnt(0) in the main loop. Swizzle: slot ^ ((row>>1)&3), 2-way = free.
// ---------------------------------------------------------------------------
__device__ __forceinline__ short8 frag32(const ushort_t* base, int row, int slot) {
    const char* p = reinterpret_cast<const char*>(base) +
                    row * 64 + (((slot ^ ((row >> 1) & 3)) & 3) << 4);
    return *reinterpret_cast<const short8*>(p);
}

template <int EPI>
__global__ __launch_bounds__(256) void gemm_bf3(
    const ushort_t* __restrict__ Ahg, const ushort_t* __restrict__ Alg, int lda,
    const ushort_t* __restrict__ Bhg, const ushort_t* __restrict__ Blg, int ldb,
    float* __restrict__ C, int ldc, size_t czstride,
    const float* __restrict__ bias, int kLen)
{
    __shared__ ushort_t Ahs[2][128 * 32];
    __shared__ ushort_t Als[2][128 * 32];
    __shared__ ushort_t Bhs[2][128 * 32];
    __shared__ ushort_t Bls[2][128 * 32];

    const int tid = threadIdx.x;
    const int lane = tid & 63;
    const int w = tid >> 6;
    const int wr = w >> 1, wc = w & 1;
    const int fr = lane & 15, fg = lane >> 4;
    const int m0 = blockIdx.y * 128;
    const int n0 = blockIdx.x * 128;
    const int kOff = blockIdx.z * kLen;
    Ahg += kOff; Alg += kOff; Bhg += kOff; Blg += kOff;
    C += (size_t)blockIdx.z * czstride;

    // staging coords: 512 granules/plane per K-tile; thread owns {tid, tid+256}
    const int g0 = tid, g1 = tid + 256;
    const int r0 = g0 >> 2, s0 = g0 & 3;
    const int r1 = g1 >> 2, s1 = g1 & 3;
    const int c0 = (s0 ^ ((r0 >> 1) & 3)) << 3;   // pre-swizzled source col
    const int c1 = (s1 ^ ((r1 >> 1) & 3)) << 3;
    const size_t a0 = (size_t)(m0 + r0) * lda + c0;
    const size_t a1 = (size_t)(m0 + r1) * lda + c1;
    const size_t b0 = (size_t)(n0 + r0) * ldb + c0;
    const size_t b1 = (size_t)(n0 + r1) * ldb + c1;
    const int l0 = g0 * 8, l1 = g1 * 8;

    f32x4 zero = {0.f, 0.f, 0.f, 0.f};
    f32x4 acc[4][4];
#pragma unroll
    for (int i = 0; i < 4; ++i)
#pragma unroll
        for (int j = 0; j < 4; ++j) acc[i][j] = zero;

    auto STAGE = [&](int buf, int kt) {
        const int k0 = kt * 32;
        gload_lds16(Ahg + a0 + k0, &Ahs[buf][l0]);
        gload_lds16(Ahg + a1 + k0, &Ahs[buf][l1]);
        gload_lds16(Alg + a0 + k0, &Als[buf][l0]);
        gload_lds16(Alg + a1 + k0, &Als[buf][l1]);
        gload_lds16(Bhg + b0 + k0, &Bhs[buf][l0]);
        gload_lds16(Bhg + b1 + k0, &Bhs[buf][l1]);
        gload_lds16(Blg + b0 + k0, &Bls[buf][l0]);
        gload_lds16(Blg + b1 + k0, &Bls[buf][l1]);
    };

    const int nt = kLen >> 5;
    STAGE(0, 0);

    for (int t = 0; t < nt; ++t) {
        const int cur = t & 1;
        if (t + 1 < nt) {
            STAGE(cur ^ 1, t + 1);
            asm volatile("s_waitcnt vmcnt(8)" ::: "memory");
        } else {
            asm volatile("s_waitcnt vmcnt(0)" ::: "memory");
        }
        __builtin_amdgcn_sched_barrier(0);
        __builtin_amdgcn_s_barrier();
        __builtin_amdgcn_sched_barrier(0);

        short8 ah[4], bh[4], xf[4];
#pragma unroll
        for (int i = 0; i < 4; ++i) {
            ah[i] = frag32(Ahs[cur], wr * 64 + i * 16 + fr, fg);
            bh[i] = frag32(Bhs[cur], wc * 64 + i * 16 + fr, fg);
        }
#pragma unroll
        for (int i = 0; i < 4; ++i)
#pragma unroll
            for (int j = 0; j < 4; ++j)
                acc[i][j] = __builtin_amdgcn_mfma_f32_16x16x32_bf16(
                    ah[i], bh[j], acc[i][j], 0, 0, 0);
#pragma unroll
        for (int i = 0; i < 4; ++i)
            xf[i] = frag32(Bls[cur], wc * 64 + i * 16 + fr, fg);
#pragma unroll
        for (int i = 0; i < 4; ++i)
#pragma unroll
            for (int j = 0; j < 4; ++j)
                acc[i][j] = __builtin_amdgcn_mfma_f32_16x16x32_bf16(
                    ah[i], xf[j], acc[i][j], 0, 0, 0);
#pragma unroll
        for (int i = 0; i < 4; ++i)
            xf[i] = frag32(Als[cur], wr * 64 + i * 16 + fr, fg);
#pragma unroll
        for (int i = 0; i < 4; ++i)
#pragma unroll
            for (int j = 0; j < 4; ++j)
                acc[i][j] = __builtin_amdgcn_mfma_f32_16x16x32_bf16(
                    xf[i], bh[j], acc[i][j], 0, 0, 0);

        __builtin_amdgcn_sched_barrier(0);
        __builtin_amdgcn_s_barrier();
    }

#pragma unroll
    for (int i = 0; i < 4; ++i) {
        const int mrow = m0 + wr * 64 + i * 16 + fg * 4;
#pragma unroll
        for (int j = 0; j < 4; ++j) {
            const int col = n0 + wc * 64 + j * 16 + fr;
#pragma unroll
            for (int r = 0; r < 4; ++r) {
                float v = acc[i][j][r];
                if constexpr (EPI == 1) {
                    v += bias[col];
                    v = (v > 20.f) ? v : log1pf(__expf(v));
                }
                C[(size_t)(mrow + r) * ldc + col] = v;
            }
        }
    }
}

// ---------------------------------------------------------------------------
// Causal depthwise conv (k=4) + bias + SiLU -> planar Uh/Ul.
// ---------------------------------------------------------------------------
__global__ __launch_bounds__(256) void conv_silu(
    const float* __restrict__ XR, const float* __restrict__ cw,
    const float* __restrict__ cb, ushort_t* __restrict__ Uh,
    ushort_t* __restrict__ Ul)
{
    const int idx = blockIdx.x * 256 + threadIdx.x;
    const int d = idx & (D_INNER - 1);
    const int m = idx >> 11;
    const int l = m & (SEQ - 1);

    float acc = cb[d];
#pragma unroll
    for (int j = 0; j < D_CONV; ++j) {
        const int ll = l - (D_CONV - 1) + j;
        if (ll >= 0)
            acc = fmaf(XR[(size_t)(m - (D_CONV - 1) + j) * NPROJ + d],
                       cw[d * D_CONV + j], acc);
    }
    const float s = acc / (1.f + __expf(-acc));
    const unsigned short h = f2bf(s);
    Uh[idx] = h;
    Ul[idx] = f2bf(s - bf2f(h));
}

// ---------------------------------------------------------------------------
// Chunked selective scan, lane = channel; h[16], a[16] in regs. LC=32.
// ---------------------------------------------------------------------------
__global__ __launch_bounds__(256) void scan_phase1(
    const float* __restrict__ DELTA, const ushort_t* __restrict__ Uh,
    const ushort_t* __restrict__ Ul, const float* __restrict__ XDBL,
    const float* __restrict__ A_log, float* __restrict__ P,
    float* __restrict__ HL)
{
    const int tid = threadIdx.x;
    const int d = blockIdx.x * 256 + tid;
    const int c = blockIdx.y;
    const int b = blockIdx.z;

    float a[16];
#pragma unroll
    for (int q = 0; q < 4; ++q) {
        const float4 v = *reinterpret_cast<const float4*>(A_log + (size_t)d * 16 + q * 4);
        a[q * 4 + 0] = -__expf(v.x);
        a[q * 4 + 1] = -__expf(v.y);
        a[q * 4 + 2] = -__expf(v.z);
        a[q * 4 + 3] = -__expf(v.w);
    }
    float h[16];
#pragma unroll
    for (int n = 0; n < 16; ++n) h[n] = 0.f;
    float sd = 0.f;
    const size_t base = (size_t)b * SEQ + (size_t)c * LC;

#pragma unroll 4
    for (int t = 0; t < LC; ++t) {
        const size_t m = base + t;
        const float delta = DELTA[m * D_INNER + d];
        const float u = bf2f(Uh[m * D_INNER + d]) + bf2f(Ul[m * D_INNER + d]);
        const float du = delta * u;
        const float* xb = XDBL + m * XDBL_K + DT_RANK;   // wave-uniform
        float bv[16];
#pragma unroll
        for (int n = 0; n < 16; ++n) bv[n] = xb[n];
        sd += delta;
#pragma unroll
        for (int n = 0; n < 16; ++n) {
            const float dA = __expf(delta * a[n]);
            h[n] = fmaf(dA, h[n], du * bv[n]);
        }
    }

    const size_t idx = (size_t)c * SLANES + ((size_t)b * D_INNER + d) * 16;
#pragma unroll
    for (int q = 0; q < 4; ++q) {
        float4 pv, hv;
        pv.x = __expf(a[q * 4 + 0] * sd);
        pv.y = __expf(a[q * 4 + 1] * sd);
        pv.z = __expf(a[q * 4 + 2] * sd);
        pv.w = __expf(a[q * 4 + 3] * sd);
        hv.x = h[q * 4 + 0]; hv.y = h[q * 4 + 1];
        hv.z = h[q * 4 + 2]; hv.w = h[q * 4 + 3];
        *reinterpret_cast<float4*>(&P[idx + q * 4]) = pv;
        *reinterpret_cast<float4*>(&HL[idx + q * 4]) = hv;
    }
}

__global__ __launch_bounds__(256) void scan_phase2(
    float* __restrict__ P, const float* __restrict__ HL)
{
    const int t = blockIdx.x * 256 + threadIdx.x;
    float h = 0.f;
#pragma unroll 4
    for (int c = 0; c < NC; ++c) {
        const size_t idx = (size_t)c * SLANES + t;
        const float p = P[idx];
        const float hl = HL[idx];
        P[idx] = h;
        h = fmaf(p, h, hl);
    }
}

__global__ __launch_bounds__(256) void scan_phase3(
    const float* __restrict__ DELTA, const ushort_t* __restrict__ Uh,
    const ushort_t* __restrict__ Ul, const float* __restrict__ XDBL,
    const float* __restrict__ XR, const float* __restrict__ A_log,
    const float* __restrict__ Dp, const float* __restrict__ H0,
    ushort_t* __restrict__ Yh, ushort_t* __restrict__ Yl)
{
    const int tid = threadIdx.x;
    const int d = blockIdx.x * 256 + tid;
    const int c = blockIdx.y;
    const int b = blockIdx.z;

    float a[16];
#pragma unroll
    for (int q = 0; q < 4; ++q) {
        const float4 v = *reinterpret_cast<const float4*>(A_log + (size_t)d * 16 + q * 4);
        a[q * 4 + 0] = -__expf(v.x);
        a[q * 4 + 1] = -__expf(v.y);
        a[q * 4 + 2] = -__expf(v.z);
        a[q * 4 + 3] = -__expf(v.w);
    }
    const float Dd = Dp[d];

    float h[16];
    const size_t idx0 = (size_t)c * SLANES + ((size_t)b * D_INNER + d) * 16;
#pragma unroll
    for (int q = 0; q < 4; ++q) {
        const float4 v = *reinterpret_cast<const float4*>(&H0[idx0 + q * 4]);
        h[q * 4 + 0] = v.x; h[q * 4 + 1] = v.y;
        h[q * 4 + 2] = v.z; h[q * 4 + 3] = v.w;
    }
    const size_t base = (size_t)b * SEQ + (size_t)c * LC;

#pragma unroll 4
    for (int t = 0; t < LC; ++t) {
        const size_t m = base + t;
        const float delta = DELTA[m * D_INNER + d];
        const float u = bf2f(Uh[m * D_INNER + d]) + bf2f(Ul[m * D_INNER + d]);
        const float du = delta * u;
        const float* xb = XDBL + m * XDBL_K + DT_RANK;   // wave-uniform
        float bv[16], cv[16];
#pragma unroll
        for (int n = 0; n < 16; ++n) bv[n] = xb[n];
#pragma unroll
        for (int n = 0; n < 16; ++n) cv[n] = xb[16 + n];

        float y0 = 0.f, y1 = 0.f, y2 = 0.f, y3 = 0.f;
#pragma unroll
        for (int n = 0; n < 4; ++n) {
            const float dA0 = __expf(delta * a[n]);
            const float dA1 = __expf(delta * a[n + 4]);
            const float dA2 = __expf(delta * a[n + 8]);
            const float dA3 = __expf(delta * a[n + 12]);
            h[n]      = fmaf(dA0, h[n],      du * bv[n]);
            h[n + 4]  = fmaf(dA1, h[n + 4],  du * bv[n + 4]);
            h[n + 8]  = fmaf(dA2, h[n + 8],  du * bv[n + 8]);
            h[n + 12] = fmaf(dA3, h[n + 12], du * bv[n + 12]);
            y0 = fmaf(h[n],      cv[n],      y0);
            y1 = fmaf(h[n + 4],  cv[n + 4],  y1);
            y2 = fmaf(h[n + 8],  cv[n + 8],  y2);
            y3 = fmaf(h[n + 12], cv[n + 12], y3);
        }
        const float y = (y0 + y1) + (y2 + y3) + u * Dd;
        const float r = XR[m * NPROJ + D_INNER + d];
        const float sr = r / (1.f + __expf(-r));
        const float yg = y * sr;
        const unsigned short hh = f2bf(yg);
        Yh[m * D_INNER + d] = hh;
        Yl[m * D_INNER + d] = f2bf(yg - bf2f(hh));
    }
}

// ---------------------------------------------------------------------------
// split-K reductions
// ---------------------------------------------------------------------------
__global__ __launch_bounds__(256) void reduce_xdbl(
    const float* __restrict__ PP, float* __restrict__ XDBL,
    ushort_t* __restrict__ XDh, ushort_t* __restrict__ XDl)
{
    const int t = blockIdx.x * 256 + threadIdx.x;
    const int m = t / XDBL_K;
    const int n = t - m * XDBL_K;
    float s = 0.f;
#pragma unroll
    for (int z = 0; z < 16; ++z)
        s += PP[(size_t)z * MROWS * 128 + (size_t)m * 128 + n];
    XDBL[t] = s;
    if (n < DT_RANK) {
        const unsigned short h = f2bf(s);
        XDh[(size_t)m * DT_RANK + n] = h;
        XDl[(size_t)m * DT_RANK + n] = f2bf(s - bf2f(h));
    }
}

__global__ __launch_bounds__(256) void reduce_out(
    const float* __restrict__ OP, float* __restrict__ out)
{
    const int t = blockIdx.x * 256 + threadIdx.x;
    float4 s = *reinterpret_cast<const float4*>(OP + (size_t)t * 4);
#pragma unroll
    for (int z = 1; z < 4; ++z) {
        const float4 v = *reinterpret_cast<const float4*>(
            OP + (size_t)z * MROWS * DIM + (size_t)t * 4);
        s.x += v.x; s.y += v.y; s.z += v.z; s.w += v.w;
    }
    *reinterpret_cast<float4*>(out + (size_t)t * 4) = s;
}

// ---------------------------------------------------------------------------
extern "C" void kernel_launch(void* const* d_in, const int* in_sizes, int n_in,
                              void* d_out, int out_size, void* d_ws, size_t ws_size,
                              hipStream_t stream)
{
    const float* x       = (const float*)d_in[0];
    const float* in_w    = (const float*)d_in[1];
    const float* conv_w  = (const float*)d_in[2];
    const float* conv_b  = (const float*)d_in[3];
    const float* xproj_w = (const float*)d_in[4];
    const float* dt_w    = (const float*)d_in[5];
    const float* dt_b    = (const float*)d_in[6];
    const float* A_log   = (const float*)d_in[7];
    const float* Dp      = (const float*)d_in[8];
    const float* out_w   = (const float*)d_in[9];
    float* out = (float*)d_out;

    const size_t MF = 1024 * 1024;
    float* WF    = (float*)d_ws;
    float* XR    = WF;                 // [0,8M) in_proj out; OP reuses [0,8M) after scan3
    float* DELTA = WF + 8 * MF;        // [8,12M)
    float* XDBL  = WF + 12 * MF;       // 2048*96 floats
    float* PP    = WF + 13 * MF;       // [13,17M) xdbl partials (dead before scan)
    float* P     = WF + 13 * MF;       // [13,15M)   (LC=32 -> 2M floats)
    float* HL    = WF + 17 * MF;       // [17,19M); Yl reuses after phase2
    float* OP    = WF;                 // out partials, 4 x 2M floats = [0,8M)

    // bf16 planar buffers (ushort units), base at 21M floats
    ushort_t* UB  = (ushort_t*)(WF + 21 * MF);
    ushort_t* xh  = UB;                         // 2M   } dead after in_proj:
    ushort_t* xl  = UB + 2 * MF;                // 2M   }  reused by Uh/Ul/Yh
    ushort_t* iwh = UB + 4 * MF;                // 4M   }
    ushort_t* iwl = UB + 8 * MF;                // 4M   }
    ushort_t* Uh  = UB;                         // 4M (conv output, 2048x2048)
    ushort_t* Ul  = UB + 4 * MF;                // 4M
    ushort_t* Yh  = UB + 8 * MF;                // 4M (scan3 output, 2048x2048)
    ushort_t* Yl  = (ushort_t*)(WF + 17 * MF);  // 4M ushorts in dead HL region
    ushort_t* xph = UB + 12 * MF;               // 256K (128 x 2048, padded)
    ushort_t* xpl = xph + 256 * 1024;           // 256K
    ushort_t* dth = xpl + 256 * 1024;           // 128K
    ushort_t* dtl = dth + 128 * 1024;           // 128K
    ushort_t* owh = dtl + 128 * 1024;           // 2M
    ushort_t* owl = owh + 2 * MF;               // 2M
    ushort_t* XDh = owl + 2 * MF;               // 128K
    ushort_t* XDl = XDh + 128 * 1024;           // 128K

    const dim3 blk(256);

    // 0) split all GEMM operands to planar bf16 hi/lo
    split_all<<<SPLIT_GRANULES / 256, blk, 0, stream>>>(
        x, in_w, xproj_w, dt_w, out_w,
        xh, xl, iwh, iwl, xph, xpl, dth, dtl, owh, owl);

    // 1) in_proj: XR = X @ in_w^T (K=1024, nt=32)
    gemm_bf3<0><<<dim3(NPROJ / 128, MROWS / 128, 1), blk, 0, stream>>>(
        xh, xl, DIM, iwh, iwl, DIM, XR, NPROJ, 0, nullptr, DIM);

    // 2) conv + silu -> Uh/Ul
    conv_silu<<<(MROWS * D_INNER) / 256, blk, 0, stream>>>(XR, conv_w, conv_b, Uh, Ul);

    // 3) x_dbl = U @ xproj_w^T (N 96->128 pad, split-K=16, kLen=128)
    gemm_bf3<0><<<dim3(1, MROWS / 128, 16), blk, 0, stream>>>(
        Uh, Ul, D_INNER, xph, xpl, D_INNER, PP, 128, (size_t)MROWS * 128, nullptr, D_INNER / 16);
    reduce_xdbl<<<(MROWS * XDBL_K) / 256, blk, 0, stream>>>(PP, XDBL, XDh, XDl);

    // 4) DELTA = softplus(XDBL[:, :64] @ dt_w^T + dt_b) (K=64, nt=2)
    gemm_bf3<1><<<dim3(D_INNER / 128, MROWS / 128, 1), blk, 0, stream>>>(
        XDh, XDl, DT_RANK, dth, dtl, DT_RANK, DELTA, D_INNER, 0, dt_b, DT_RANK);

    // 5) chunked selective scan (LC=32)
    scan_phase1<<<dim3(D_INNER / 256, NC, BATCH), blk, 0, stream>>>(
        DELTA, Uh, Ul, XDBL, A_log, P, HL);
    scan_phase2<<<SLANES / 256, blk, 0, stream>>>(P, HL);
    scan_phase3<<<dim3(D_INNER / 256, NC, BATCH), blk, 0, stream>>>(
        DELTA, Uh, Ul, XDBL, XR, A_log, Dp, P, Yh, Yl);

    // 6) out = Y @ out_w^T (split-K=4, kLen=512)
    gemm_bf3<0><<<dim3(DIM / 128, MROWS / 128, 4), blk, 0, stream>>>(
        Yh, Yl, D_INNER, owh, owl, D_INNER, OP, DIM, (size_t)MROWS * DIM, nullptr, D_INNER / 4);
    reduce_out<<<(MROWS * DIM / 4) / 256, blk, 0, stream>>>(OP, out);
}

// Round 10
// 231.743 us; speedup vs baseline: 1.0241x; 1.0241x over previous
//
#include <hip/hip_runtime.h>
#include <hip/hip_bf16.h>
#include <stdint.h>

// Shapes
#define DIM      1024
#define D_STATE  16
#define D_CONV   4
#define D_INNER  2048
#define DT_RANK  64
#define BATCH    2
#define SEQ      1024
#define MROWS    (BATCH * SEQ)            // 2048
#define NPROJ    (2 * D_INNER)            // 4096
#define XDBL_K   (DT_RANK + 2 * D_STATE)  // 96

// chunked scan
#define LC       32
#define NC       (SEQ / LC)               // 32
#define SLANES   (BATCH * D_INNER * D_STATE) // 65536

typedef __attribute__((ext_vector_type(8))) short short8;
typedef __attribute__((ext_vector_type(4))) float f32x4;
typedef unsigned short ushort_t;

__device__ __forceinline__ unsigned short f2bf(float f) {
    __hip_bfloat16 b = __float2bfloat16(f);
    return *reinterpret_cast<unsigned short*>(&b);
}
__device__ __forceinline__ float bf2f(unsigned short u) {
    __hip_bfloat16 b;
    *reinterpret_cast<unsigned short*>(&b) = u;
    return __bfloat162float(b);
}

__device__ __forceinline__ void gload_lds16(const unsigned short* g, unsigned short* l) {
    __builtin_amdgcn_global_load_lds(
        (const __attribute__((address_space(1))) void*)g,
        (__attribute__((address_space(3))) void*)l,
        16, 0, 0);
}

// ---------------------------------------------------------------------------
// Preamble: split all fp32 GEMM operand tensors into planar bf16 hi/lo.
// ---------------------------------------------------------------------------
#define SG0 524288    // x        granules (K/4 per row)
#define SG1 1048576   // in_w
#define SG2 65536     // xproj (128 rows pad)
#define SG3 32768     // dt_w
#define SG4 524288    // out_w
#define SPLIT_GRANULES (SG0 + SG1 + SG2 + SG3 + SG4)   // 2195456

__global__ __launch_bounds__(256) void split_all(
    const float* __restrict__ x,   const float* __restrict__ in_w,
    const float* __restrict__ xpw, const float* __restrict__ dtw,
    const float* __restrict__ ow,
    ushort_t* __restrict__ xh,   ushort_t* __restrict__ xl,
    ushort_t* __restrict__ iwh,  ushort_t* __restrict__ iwl,
    ushort_t* __restrict__ xph,  ushort_t* __restrict__ xpl,
    ushort_t* __restrict__ dth,  ushort_t* __restrict__ dtl,
    ushort_t* __restrict__ owh,  ushort_t* __restrict__ owl)
{
    int g = blockIdx.x * 256 + threadIdx.x;
    const float* src; int K, rows_src; ushort_t *dh, *dl;
    if (g < SG0)                      { src = x;    K = 1024; rows_src = 2048; dh = xh;  dl = xl; }
    else if ((g -= SG0) < SG1)        { src = in_w; K = 1024; rows_src = 4096; dh = iwh; dl = iwl; }
    else if ((g -= SG1) < SG2)        { src = xpw;  K = 2048; rows_src = 96;   dh = xph; dl = xpl; }
    else if ((g -= SG2) < SG3)        { src = dtw;  K = 64;   rows_src = 2048; dh = dth; dl = dtl; }
    else                              { g -= SG3;   src = ow; K = 2048; rows_src = 1024; dh = owh; dl = owl; }

    const int kq = K >> 2;
    const int r = g / kq;
    const int k4 = (g - r * kq) << 2;
    float4 v = make_float4(0.f, 0.f, 0.f, 0.f);
    if (r < rows_src)
        v = *reinterpret_cast<const float4*>(src + (size_t)r * K + k4);
    const unsigned short h0 = f2bf(v.x), h1 = f2bf(v.y), h2 = f2bf(v.z), h3 = f2bf(v.w);
    const unsigned short l0 = f2bf(v.x - bf2f(h0)), l1 = f2bf(v.y - bf2f(h1));
    const unsigned short l2 = f2bf(v.z - bf2f(h2)), l3 = f2bf(v.w - bf2f(h3));
    *reinterpret_cast<ushort4*>(dh + (size_t)r * K + k4) = make_ushort4(h0, h1, h2, h3);
    *reinterpret_cast<ushort4*>(dl + (size_t)r * K + k4) = make_ushort4(l0, l1, l2, l3);
}

// ---------------------------------------------------------------------------
// Planar 3-pass bf16 MFMA GEMM (NT): C = A @ B^T, fp32 accum.
// AhBh + AhBl + AlBh. 128x128 tile, BK=64, 4 waves, global_load_lds(16B)
// staging with pre-swizzled source cols; XOR-swizzled ds_read_b128.
// (round-7 proven core: single buffer, 2 barriers per K-tile)
// ---------------------------------------------------------------------------
__device__ __forceinline__ short8 frag_ld(const unsigned short* base, int row, int slot) {
    const char* p = reinterpret_cast<const char*>(base) +
                    row * 128 + (((slot ^ (row & 7)) & 7) << 4);
    return *reinterpret_cast<const short8*>(p);
}

template <int EPI>
__global__ __launch_bounds__(256) void gemm_bf3(
    const ushort_t* __restrict__ Ahg, const ushort_t* __restrict__ Alg, int lda,
    const ushort_t* __restrict__ Bhg, const ushort_t* __restrict__ Blg, int ldb,
    float* __restrict__ C, int ldc, size_t czstride,
    const float* __restrict__ bias, int kLen)
{
    __shared__ ushort_t Ahs[128 * 64];
    __shared__ ushort_t Als[128 * 64];
    __shared__ ushort_t Bhs[128 * 64];
    __shared__ ushort_t Bls[128 * 64];

    const int tid = threadIdx.x;
    const int lane = tid & 63;
    const int w = tid >> 6;
    const int wr = w >> 1, wc = w & 1;
    const int fr = lane & 15, fg = lane >> 4;
    const int m0 = blockIdx.y * 128;
    const int n0 = blockIdx.x * 128;
    const int kOff = blockIdx.z * kLen;
    Ahg += kOff; Alg += kOff; Bhg += kOff; Blg += kOff;
    C += (size_t)blockIdx.z * czstride;

    f32x4 zero = {0.f, 0.f, 0.f, 0.f};
    f32x4 acc[4][4];
#pragma unroll
    for (int i = 0; i < 4; ++i)
#pragma unroll
        for (int j = 0; j < 4; ++j) acc[i][j] = zero;

    for (int k0 = 0; k0 < kLen; k0 += 64) {
#pragma unroll
        for (int it = 0; it < 4; ++it) {
            const int f = it * 256 + tid;
            const int row = f >> 3;
            const int gc = ((f & 7) ^ (row & 7)) << 3;   // pre-swizzled source col
            const size_t ga = (size_t)(m0 + row) * lda + k0 + gc;
            const size_t gb = (size_t)(n0 + row) * ldb + k0 + gc;
            gload_lds16(Ahg + ga, &Ahs[f * 8]);
            gload_lds16(Alg + ga, &Als[f * 8]);
            gload_lds16(Bhg + gb, &Bhs[f * 8]);
            gload_lds16(Blg + gb, &Bls[f * 8]);
        }
        __syncthreads();

#pragma unroll
        for (int kk = 0; kk < 2; ++kk) {
            short8 ah[4], bh[4], xf[4];
#pragma unroll
            for (int i = 0; i < 4; ++i) {
                ah[i] = frag_ld(Ahs, wr * 64 + i * 16 + fr, kk * 4 + fg);
                bh[i] = frag_ld(Bhs, wc * 64 + i * 16 + fr, kk * 4 + fg);
            }
#pragma unroll
            for (int i = 0; i < 4; ++i)
#pragma unroll
                for (int j = 0; j < 4; ++j)
                    acc[i][j] = __builtin_amdgcn_mfma_f32_16x16x32_bf16(
                        ah[i], bh[j], acc[i][j], 0, 0, 0);
            // bl pass
#pragma unroll
            for (int i = 0; i < 4; ++i)
                xf[i] = frag_ld(Bls, wc * 64 + i * 16 + fr, kk * 4 + fg);
#pragma unroll
            for (int i = 0; i < 4; ++i)
#pragma unroll
                for (int j = 0; j < 4; ++j)
                    acc[i][j] = __builtin_amdgcn_mfma_f32_16x16x32_bf16(
                        ah[i], xf[j], acc[i][j], 0, 0, 0);
            // al pass
#pragma unroll
            for (int i = 0; i < 4; ++i)
                xf[i] = frag_ld(Als, wr * 64 + i * 16 + fr, kk * 4 + fg);
#pragma unroll
            for (int i = 0; i < 4; ++i)
#pragma unroll
                for (int j = 0; j < 4; ++j)
                    acc[i][j] = __builtin_amdgcn_mfma_f32_16x16x32_bf16(
                        xf[i], bh[j], acc[i][j], 0, 0, 0);
        }
        __syncthreads();
    }

#pragma unroll
    for (int i = 0; i < 4; ++i) {
        const int mrow = m0 + wr * 64 + i * 16 + fg * 4;
#pragma unroll
        for (int j = 0; j < 4; ++j) {
            const int col = n0 + wc * 64 + j * 16 + fr;
#pragma unroll
            for (int r = 0; r < 4; ++r) {
                float v = acc[i][j][r];
                if constexpr (EPI == 1) {
                    v += bias[col];
                    v = (v > 20.f) ? v : log1pf(__expf(v));
                }
                C[(size_t)(mrow + r) * ldc + col] = v;
            }
        }
    }
}

// ---------------------------------------------------------------------------
// Causal depthwise conv (k=4) + bias + SiLU -> planar Uh/Ul.
// ---------------------------------------------------------------------------
__global__ __launch_bounds__(256) void conv_silu(
    const float* __restrict__ XR, const float* __restrict__ cw,
    const float* __restrict__ cb, ushort_t* __restrict__ Uh,
    ushort_t* __restrict__ Ul)
{
    const int idx = blockIdx.x * 256 + threadIdx.x;
    const int d = idx & (D_INNER - 1);
    const int m = idx >> 11;
    const int l = m & (SEQ - 1);

    float acc = cb[d];
#pragma unroll
    for (int j = 0; j < D_CONV; ++j) {
        const int ll = l - (D_CONV - 1) + j;
        if (ll >= 0)
            acc = fmaf(XR[(size_t)(m - (D_CONV - 1) + j) * NPROJ + d],
                       cw[d * D_CONV + j], acc);
    }
    const float s = acc / (1.f + __expf(-acc));
    const unsigned short h = f2bf(s);
    Uh[idx] = h;
    Ul[idx] = f2bf(s - bf2f(h));
}

// ---------------------------------------------------------------------------
// Chunked selective scan, lane = channel; h[16], a[16] in regs. LC=32.
// ---------------------------------------------------------------------------
__global__ __launch_bounds__(256) void scan_phase1(
    const float* __restrict__ DELTA, const ushort_t* __restrict__ Uh,
    const ushort_t* __restrict__ Ul, const float* __restrict__ XDBL,
    const float* __restrict__ A_log, float* __restrict__ P,
    float* __restrict__ HL)
{
    const int tid = threadIdx.x;
    const int d = blockIdx.x * 256 + tid;
    const int c = blockIdx.y;
    const int b = blockIdx.z;

    float a[16];
#pragma unroll
    for (int q = 0; q < 4; ++q) {
        const float4 v = *reinterpret_cast<const float4*>(A_log + (size_t)d * 16 + q * 4);
        a[q * 4 + 0] = -__expf(v.x);
        a[q * 4 + 1] = -__expf(v.y);
        a[q * 4 + 2] = -__expf(v.z);
        a[q * 4 + 3] = -__expf(v.w);
    }
    float h[16];
#pragma unroll
    for (int n = 0; n < 16; ++n) h[n] = 0.f;
    float sd = 0.f;
    const size_t base = (size_t)b * SEQ + (size_t)c * LC;

#pragma unroll 4
    for (int t = 0; t < LC; ++t) {
        const size_t m = base + t;
        const float delta = DELTA[m * D_INNER + d];
        const float u = bf2f(Uh[m * D_INNER + d]) + bf2f(Ul[m * D_INNER + d]);
        const float du = delta * u;
        const float* xb = XDBL + m * XDBL_K + DT_RANK;   // wave-uniform
        float bv[16];
#pragma unroll
        for (int n = 0; n < 16; ++n) bv[n] = xb[n];
        sd += delta;
#pragma unroll
        for (int n = 0; n < 16; ++n) {
            const float dA = __expf(delta * a[n]);
            h[n] = fmaf(dA, h[n], du * bv[n]);
        }
    }

    const size_t idx = (size_t)c * SLANES + ((size_t)b * D_INNER + d) * 16;
#pragma unroll
    for (int q = 0; q < 4; ++q) {
        float4 pv, hv;
        pv.x = __expf(a[q * 4 + 0] * sd);
        pv.y = __expf(a[q * 4 + 1] * sd);
        pv.z = __expf(a[q * 4 + 2] * sd);
        pv.w = __expf(a[q * 4 + 3] * sd);
        hv.x = h[q * 4 + 0]; hv.y = h[q * 4 + 1];
        hv.z = h[q * 4 + 2]; hv.w = h[q * 4 + 3];
        *reinterpret_cast<float4*>(&P[idx + q * 4]) = pv;
        *reinterpret_cast<float4*>(&HL[idx + q * 4]) = hv;
    }
}

__global__ __launch_bounds__(256) void scan_phase2(
    float* __restrict__ P, const float* __restrict__ HL)
{
    const int t = blockIdx.x * 256 + threadIdx.x;
    float h = 0.f;
#pragma unroll 4
    for (int c = 0; c < NC; ++c) {
        const size_t idx = (size_t)c * SLANES + t;
        const float p = P[idx];
        const float hl = HL[idx];
        P[idx] = h;
        h = fmaf(p, h, hl);
    }
}

__global__ __launch_bounds__(256) void scan_phase3(
    const float* __restrict__ DELTA, const ushort_t* __restrict__ Uh,
    const ushort_t* __restrict__ Ul, const float* __restrict__ XDBL,
    const float* __restrict__ XR, const float* __restrict__ A_log,
    const float* __restrict__ Dp, const float* __restrict__ H0,
    ushort_t* __restrict__ Yh, ushort_t* __restrict__ Yl)
{
    const int tid = threadIdx.x;
    const int d = blockIdx.x * 256 + tid;
    const int c = blockIdx.y;
    const int b = blockIdx.z;

    float a[16];
#pragma unroll
    for (int q = 0; q < 4; ++q) {
        const float4 v = *reinterpret_cast<const float4*>(A_log + (size_t)d * 16 + q * 4);
        a[q * 4 + 0] = -__expf(v.x);
        a[q * 4 + 1] = -__expf(v.y);
        a[q * 4 + 2] = -__expf(v.z);
        a[q * 4 + 3] = -__expf(v.w);
    }
    const float Dd = Dp[d];

    float h[16];
    const size_t idx0 = (size_t)c * SLANES + ((size_t)b * D_INNER + d) * 16;
#pragma unroll
    for (int q = 0; q < 4; ++q) {
        const float4 v = *reinterpret_cast<const float4*>(&H0[idx0 + q * 4]);
        h[q * 4 + 0] = v.x; h[q * 4 + 1] = v.y;
        h[q * 4 + 2] = v.z; h[q * 4 + 3] = v.w;
    }
    const size_t base = (size_t)b * SEQ + (size_t)c * LC;

#pragma unroll 4
    for (int t = 0; t < LC; ++t) {
        const size_t m = base + t;
        const float delta = DELTA[m * D_INNER + d];
        const float u = bf2f(Uh[m * D_INNER + d]) + bf2f(Ul[m * D_INNER + d]);
        const float du = delta * u;
        const float* xb = XDBL + m * XDBL_K + DT_RANK;   // wave-uniform
        float bv[16], cv[16];
#pragma unroll
        for (int n = 0; n < 16; ++n) bv[n] = xb[n];
#pragma unroll
        for (int n = 0; n < 16; ++n) cv[n] = xb[16 + n];

        float y0 = 0.f, y1 = 0.f, y2 = 0.f, y3 = 0.f;
#pragma unroll
        for (int n = 0; n < 4; ++n) {
            const float dA0 = __expf(delta * a[n]);
            const float dA1 = __expf(delta * a[n + 4]);
            const float dA2 = __expf(delta * a[n + 8]);
            const float dA3 = __expf(delta * a[n + 12]);
            h[n]      = fmaf(dA0, h[n],      du * bv[n]);
            h[n + 4]  = fmaf(dA1, h[n + 4],  du * bv[n + 4]);
            h[n + 8]  = fmaf(dA2, h[n + 8],  du * bv[n + 8]);
            h[n + 12] = fmaf(dA3, h[n + 12], du * bv[n + 12]);
            y0 = fmaf(h[n],      cv[n],      y0);
            y1 = fmaf(h[n + 4],  cv[n + 4],  y1);
            y2 = fmaf(h[n + 8],  cv[n + 8],  y2);
            y3 = fmaf(h[n + 12], cv[n + 12], y3);
        }
        const float y = (y0 + y1) + (y2 + y3) + u * Dd;
        const float r = XR[m * NPROJ + D_INNER + d];
        const float sr = r / (1.f + __expf(-r));
        const float yg = y * sr;
        const unsigned short hh = f2bf(yg);
        Yh[m * D_INNER + d] = hh;
        Yl[m * D_INNER + d] = f2bf(yg - bf2f(hh));
    }
}

// ---------------------------------------------------------------------------
// split-K reductions
// ---------------------------------------------------------------------------
__global__ __launch_bounds__(256) void reduce_xdbl(
    const float* __restrict__ PP, float* __restrict__ XDBL,
    ushort_t* __restrict__ XDh, ushort_t* __restrict__ XDl)
{
    const int t = blockIdx.x * 256 + threadIdx.x;
    const int m = t / XDBL_K;
    const int n = t - m * XDBL_K;
    float s = 0.f;
#pragma unroll
    for (int z = 0; z < 16; ++z)
        s += PP[(size_t)z * MROWS * 128 + (size_t)m * 128 + n];
    XDBL[t] = s;
    if (n < DT_RANK) {
        const unsigned short h = f2bf(s);
        XDh[(size_t)m * DT_RANK + n] = h;
        XDl[(size_t)m * DT_RANK + n] = f2bf(s - bf2f(h));
    }
}

__global__ __launch_bounds__(256) void reduce_out(
    const float* __restrict__ OP, float* __restrict__ out)
{
    const int t = blockIdx.x * 256 + threadIdx.x;
    float4 s = *reinterpret_cast<const float4*>(OP + (size_t)t * 4);
#pragma unroll
    for (int z = 1; z < 4; ++z) {
        const float4 v = *reinterpret_cast<const float4*>(
            OP + (size_t)z * MROWS * DIM + (size_t)t * 4);
        s.x += v.x; s.y += v.y; s.z += v.z; s.w += v.w;
    }
    *reinterpret_cast<float4*>(out + (size_t)t * 4) = s;
}

// ---------------------------------------------------------------------------
extern "C" void kernel_launch(void* const* d_in, const int* in_sizes, int n_in,
                              void* d_out, int out_size, void* d_ws, size_t ws_size,
                              hipStream_t stream)
{
    const float* x       = (const float*)d_in[0];
    const float* in_w    = (const float*)d_in[1];
    const float* conv_w  = (const float*)d_in[2];
    const float* conv_b  = (const float*)d_in[3];
    const float* xproj_w = (const float*)d_in[4];
    const float* dt_w    = (const float*)d_in[5];
    const float* dt_b    = (const float*)d_in[6];
    const float* A_log   = (const float*)d_in[7];
    const float* Dp      = (const float*)d_in[8];
    const float* out_w   = (const float*)d_in[9];
    float* out = (float*)d_out;

    const size_t MF = 1024 * 1024;
    float* WF    = (float*)d_ws;
    float* XR    = WF;                 // [0,8M) in_proj out; OP reuses [0,8M) after scan3
    float* DELTA = WF + 8 * MF;        // [8,12M)
    float* XDBL  = WF + 12 * MF;       // 2048*96 floats
    float* PP    = WF + 13 * MF;       // [13,17M) xdbl partials (16 x 2048 x 128 floats)
    float* P     = WF + 13 * MF;       // [13,15M) after PP dead (LC=32 -> 2M floats)
    float* HL    = WF + 17 * MF;       // [17,19M); Yl reuses after phase2
    float* OP    = WF;                 // out partials, 4 x 2M floats = [0,8M)

    // bf16 planar buffers (ushort units), base at 21M floats
    ushort_t* UB  = (ushort_t*)(WF + 21 * MF);
    ushort_t* xh  = UB;                         // 2M   } dead after in_proj:
    ushort_t* xl  = UB + 2 * MF;                // 2M   }  reused by Uh/Ul/Yh
    ushort_t* iwh = UB + 4 * MF;                // 4M   }
    ushort_t* iwl = UB + 8 * MF;                // 4M   }
    ushort_t* Uh  = UB;                         // 4M (conv output, 2048x2048)
    ushort_t* Ul  = UB + 4 * MF;                // 4M
    ushort_t* Yh  = UB + 8 * MF;                // 4M (scan3 output, 2048x2048)
    ushort_t* Yl  = (ushort_t*)(WF + 17 * MF);  // 4M ushorts in dead HL region
    ushort_t* xph = UB + 12 * MF;               // 256K (128 x 2048, padded)
    ushort_t* xpl = xph + 256 * 1024;           // 256K
    ushort_t* dth = xpl + 256 * 1024;           // 128K
    ushort_t* dtl = dth + 128 * 1024;           // 128K
    ushort_t* owh = dtl + 128 * 1024;           // 2M
    ushort_t* owl = owh + 2 * MF;               // 2M
    ushort_t* XDh = owl + 2 * MF;               // 128K
    ushort_t* XDl = XDh + 128 * 1024;           // 128K

    const dim3 blk(256);

    // 0) split all GEMM operands to planar bf16 hi/lo
    split_all<<<SPLIT_GRANULES / 256, blk, 0, stream>>>(
        x, in_w, xproj_w, dt_w, out_w,
        xh, xl, iwh, iwl, xph, xpl, dth, dtl, owh, owl);

    // 1) in_proj: XR = X @ in_w^T (K=1024)
    gemm_bf3<0><<<dim3(NPROJ / 128, MROWS / 128, 1), blk, 0, stream>>>(
        xh, xl, DIM, iwh, iwl, DIM, XR, NPROJ, 0, nullptr, DIM);

    // 2) conv + silu -> Uh/Ul
    conv_silu<<<(MROWS * D_INNER) / 256, blk, 0, stream>>>(XR, conv_w, conv_b, Uh, Ul);

    // 3) x_dbl = U @ xproj_w^T (N 96->128 pad, split-K=16, kLen=128)
    gemm_bf3<0><<<dim3(1, MROWS / 128, 16), blk, 0, stream>>>(
        Uh, Ul, D_INNER, xph, xpl, D_INNER, PP, 128, (size_t)MROWS * 128, nullptr, D_INNER / 16);
    reduce_xdbl<<<(MROWS * XDBL_K) / 256, blk, 0, stream>>>(PP, XDBL, XDh, XDl);

    // 4) DELTA = softplus(XDBL[:, :64] @ dt_w^T + dt_b) (K=64)
    gemm_bf3<1><<<dim3(D_INNER / 128, MROWS / 128, 1), blk, 0, stream>>>(
        XDh, XDl, DT_RANK, dth, dtl, DT_RANK, DELTA, D_INNER, 0, dt_b, DT_RANK);

    // 5) chunked selective scan (LC=32)
    scan_phase1<<<dim3(D_INNER / 256, NC, BATCH), blk, 0, stream>>>(
        DELTA, Uh, Ul, XDBL, A_log, P, HL);
    scan_phase2<<<SLANES / 256, blk, 0, stream>>>(P, HL);
    scan_phase3<<<dim3(D_INNER / 256, NC, BATCH), blk, 0, stream>>>(
        DELTA, Uh, Ul, XDBL, XR, A_log, Dp, P, Yh, Yl);

    // 6) out = Y @ out_w^T (split-K=4, kLen=512)
    gemm_bf3<0><<<dim3(DIM / 128, MROWS / 128, 4), blk, 0, stream>>>(
        Yh, Yl, D_INNER, owh, owl, D_INNER, OP, DIM, (size_t)MROWS * DIM, nullptr, D_INNER / 4);
    reduce_out<<<(MROWS * DIM / 4) / 256, blk, 0, stream>>>(OP, out);
}